// Round 1
// 913.161 us; speedup vs baseline: 1.8169x; 1.8169x over previous
//
#include <hip/hip_runtime.h>
#include <stdint.h>

typedef float f32x4 __attribute__((ext_vector_type(4)));
typedef short s16x8 __attribute__((ext_vector_type(8)));
typedef __attribute__((address_space(1))) void gvoid_t;
typedef __attribute__((address_space(3))) void svoid_t;

static __device__ __forceinline__ unsigned short f2bf(float f) {
  uint32_t u = __builtin_bit_cast(uint32_t, f);
  return (unsigned short)((u + 0x7fffu + ((u >> 16) & 1u)) >> 16);
}
static __device__ __forceinline__ float bf2f(unsigned short h) {
  uint32_t u = ((uint32_t)h) << 16;
  return __builtin_bit_cast(float, u);
}

// ---------------- phase 0: Wo fp32 -> bf16 ----------------
__global__ void wo_to_bf16(const float* __restrict__ src,
                           unsigned short* __restrict__ dst, int n) {
  int i = blockIdx.x * 256 + threadIdx.x;
  if (i < n) dst[i] = f2bf(src[i]);
}

// ---------------- phase 0b: fold Wq,Wk,bq,bk into P, Mk, c, kappa ----------------
// softmax_g(-dist[h][g]) == softmax_g( (x P x^T)[h][g] - K2[g] ) with
//   P  = 2 Wq^T Wk,  Mk = Wk^T Wk,  c[d] = 2 sum_e Wk[e][d](bk[e]-bq[e]),
//   kappa = sum_e bk[e]^2 - 2 bq.bk ;  K2[g] = x_g Mk x_g^T + x_g.c + kappa.
// (h-only terms drop out of softmax; the max(dist,0) clamp is a no-op for
//  nondegenerate data since dist = |q_h-k_g|^2 >= 0.)
__global__ __launch_bounds__(256) void prep_attn(
    const float* __restrict__ Wq, const float* __restrict__ Wk,
    const float* __restrict__ bq, const float* __restrict__ bk,
    unsigned short* __restrict__ Phi, unsigned short* __restrict__ Plo,
    unsigned short* __restrict__ Mhi, unsigned short* __restrict__ Mlo,
    float* __restrict__ cvec, float* __restrict__ kap) {
  const int idx = blockIdx.x * 256 + threadIdx.x;  // grid 16 -> 4096 outputs
  const int d = idx >> 6, dp = idx & 63;
  float sp = 0.f, sm = 0.f;
  for (int e = 0; e < 64; ++e) {
    sp += Wq[e * 64 + d] * Wk[e * 64 + dp];
    sm += Wk[e * 64 + d] * Wk[e * 64 + dp];
  }
  sp *= 2.f;
  unsigned short ph = f2bf(sp);
  Phi[idx] = ph;
  Plo[idx] = f2bf(sp - bf2f(ph));
  unsigned short mh = f2bf(sm);
  Mhi[idx] = mh;
  Mlo[idx] = f2bf(sm - bf2f(mh));
  if (blockIdx.x == 0) {
    const int t = threadIdx.x;
    if (t < 64) {
      float s = 0.f;
      for (int e = 0; e < 64; ++e) s += Wk[e * 64 + t] * (bk[e] - bq[e]);
      cvec[t] = 2.f * s;
    }
    if (t == 0) {
      float s = 0.f;
      for (int e = 0; e < 64; ++e) s += bk[e] * (bk[e] - 2.f * bq[e]);
      *kap = s;
    }
  }
}

// ---------------- phase 1: MFMA attention mixer ----------------
// One wave per b. No barriers in the main loop (per-wave LDS slices).
// All matmuls on mfma_f32_16x16x32_bf16 with hi/lo bf16 split precision.
// Frag layouts (verified by the working gemm_bt below):
//   A/B frag: matrix row = lane&15, k = (lane>>4)*8 + j (8 contiguous)
//   C tile:   col = lane&15, row = (lane>>4)*4 + reg
__global__ __launch_bounds__(256, 3) void attn_mfma(
    const float* __restrict__ x, const float* __restrict__ v,
    const unsigned short* __restrict__ Pgh, const unsigned short* __restrict__ Pgl,
    const unsigned short* __restrict__ Mgh, const unsigned short* __restrict__ Mgl,
    const float* __restrict__ cvec, const float* __restrict__ kapp,
    unsigned short* __restrict__ Aout, int B) {
  // weight tiles shared by all 4 waves; row pitch 128B, XOR-swizzled by ((row&7)<<4)
  __shared__ __align__(16) unsigned short Ph[4096], Pl[4096], Mh[4096], Ml[4096];
  // per-wave u round-trip buffer: packed (hi<<16|lo) bf16, row pitch 256B, swizzled
  __shared__ __align__(16) unsigned int u_lds[4][16 * 64];
  // per-wave attn staging [16 rows h][40 cols], cols 16..31 permanently zero
  __shared__ __align__(16) unsigned short at_lds[4][16 * 40];

  const int tid = threadIdx.x;
  const int lane = tid & 63;
  const int wave = tid >> 6;
  const int e16 = lane & 15;
  const int q4 = lane >> 4;

  {  // stage swizzled weights (coalesced read, 16B swizzled LDS writes)
    const uint4* src[4] = {(const uint4*)Pgh, (const uint4*)Pgl,
                           (const uint4*)Mgh, (const uint4*)Mgl};
    unsigned short* dst[4] = {Ph, Pl, Mh, Ml};
#pragma unroll
    for (int a = 0; a < 4; ++a) {
      for (int c = tid; c < 512; c += 256) {
        uint4 val = src[a][c];
        int row = c >> 3;  // 8 x 16B chunks per 128B row
        int byteoff = (c * 16) ^ ((row & 7) << 4);
        *(uint4*)((char*)dst[a] + byteoff) = val;
      }
    }
    for (int i = tid; i < (4 * 16 * 40) / 2; i += 256)
      ((unsigned int*)at_lds)[i] = 0u;
  }
  __syncthreads();  // the only barrier

  float c_t[4];
#pragma unroll
  for (int t = 0; t < 4; ++t) c_t[t] = cvec[t * 16 + e16];
  const float kap = *kapp;

  unsigned int* u_w = u_lds[wave];
  unsigned short* at_w = at_lds[wave];
  const int stride = gridDim.x << 2;

#pragma unroll 1
  for (int b = blockIdx.x * 4 + wave; b < B; b += stride) {
    const float* xb = x + (size_t)b * 1024;
    const float* vb = v + (size_t)b * 1024;

    // ---- x A-frags (rows = head, k = d), direct from global, hi/lo split ----
    const f32x4* xb4 = (const f32x4*)(xb + e16 * 64 + q4 * 8);
    f32x4 xa0 = xb4[0], xa1 = xb4[1], xa2 = xb4[8], xa3 = xb4[9];

    // prefetch v for PV B-frags (transposed access); hidden under compute
    float vpre[4][8];
#pragma unroll
    for (int t = 0; t < 4; ++t)
#pragma unroll
      for (int j = 0; j < 8; ++j) {
        const int g = (q4 * 8 + j) & 15;  // &15: upper quads hit zero attn
        vpre[t][j] = vb[g * 64 + t * 16 + e16];
      }

    s16x8 xhi[2], xlo[2];
#pragma unroll
    for (int kk = 0; kk < 2; ++kk) {
      const f32x4 a = (kk == 0) ? xa0 : xa2;
      const f32x4 c = (kk == 0) ? xa1 : xa3;
#pragma unroll
      for (int j = 0; j < 4; ++j) {
        float v0 = a[j];
        unsigned short h0 = f2bf(v0);
        xhi[kk][j] = (short)h0;
        xlo[kk][j] = (short)f2bf(v0 - bf2f(h0));
        float v1 = c[j];
        unsigned short h1 = f2bf(v1);
        xhi[kk][j + 4] = (short)h1;
        xlo[kk][j + 4] = (short)f2bf(v1 - bf2f(h1));
      }
    }

    // ---- u = x@P (rows g, cols d), w = x@Mk ----
    f32x4 uacc[4], wacc[4];
#pragma unroll
    for (int t = 0; t < 4; ++t) { uacc[t] = (f32x4)(0.f); wacc[t] = (f32x4)(0.f); }
#pragma unroll
    for (int kk = 0; kk < 2; ++kk) {
#pragma unroll
      for (int t = 0; t < 4; ++t) {
        const int row = t * 16 + e16;
        const int byteoff = (row * 128 + q4 * 16 + kk * 64) ^ ((row & 7) << 4);
        s16x8 ph = *(const s16x8*)((const char*)Ph + byteoff);
        s16x8 pl = *(const s16x8*)((const char*)Pl + byteoff);
        s16x8 mh = *(const s16x8*)((const char*)Mh + byteoff);
        s16x8 ml = *(const s16x8*)((const char*)Ml + byteoff);
        uacc[t] = __builtin_amdgcn_mfma_f32_16x16x32_bf16(xhi[kk], ph, uacc[t], 0, 0, 0);
        uacc[t] = __builtin_amdgcn_mfma_f32_16x16x32_bf16(xlo[kk], ph, uacc[t], 0, 0, 0);
        uacc[t] = __builtin_amdgcn_mfma_f32_16x16x32_bf16(xhi[kk], pl, uacc[t], 0, 0, 0);
        wacc[t] = __builtin_amdgcn_mfma_f32_16x16x32_bf16(xhi[kk], mh, wacc[t], 0, 0, 0);
        wacc[t] = __builtin_amdgcn_mfma_f32_16x16x32_bf16(xlo[kk], mh, wacc[t], 0, 0, 0);
        wacc[t] = __builtin_amdgcn_mfma_f32_16x16x32_bf16(xhi[kk], ml, wacc[t], 0, 0, 0);
      }
    }

    // ---- write u (packed hi/lo) to LDS for the C-layout -> A-frag transpose ----
#pragma unroll
    for (int t = 0; t < 4; ++t)
#pragma unroll
      for (int r = 0; r < 4; ++r) {
        const float val = uacc[t][r];
        const unsigned short h = f2bf(val);
        const unsigned short lo = f2bf(val - bf2f(h));
        const int row = q4 * 4 + r;
        const int byteoff = (row * 256 + (t * 16 + e16) * 4) ^ ((row & 7) << 4);
        *(unsigned int*)((char*)u_w + byteoff) = ((unsigned int)h << 16) | lo;
      }

    // ---- K2[g] = sum_d (w[g][d]+c[d]) * x[g][d] + kappa (lane-local per row g) ----
    float k2r[4];
#pragma unroll
    for (int r = 0; r < 4; ++r) {
      float s = 0.f;
#pragma unroll
      for (int t = 0; t < 4; ++t) {
        const float xv = xb[(q4 * 4 + r) * 64 + t * 16 + e16];  // L1/L2 hit
        s = fmaf(wacc[t][r] + c_t[t], xv, s);
      }
      s += __shfl_xor(s, 1);
      s += __shfl_xor(s, 2);
      s += __shfl_xor(s, 4);
      s += __shfl_xor(s, 8);
      k2r[r] = s + kap;
    }

    // ---- ST = u @ x^T  (rows g, cols h) ----
    f32x4 st = (f32x4)(0.f);
#pragma unroll
    for (int kk = 0; kk < 2; ++kk) {
      const int base = e16 * 256 + (q4 * 8 + kk * 32) * 4;
      const int sw = (e16 & 7) << 4;
      const uint4 p0 = *(const uint4*)((const char*)u_w + (base ^ sw));
      const uint4 p1 = *(const uint4*)((const char*)u_w + ((base + 16) ^ sw));
      const unsigned int pw[8] = {p0.x, p0.y, p0.z, p0.w, p1.x, p1.y, p1.z, p1.w};
      s16x8 uh, ul;
#pragma unroll
      for (int j = 0; j < 8; ++j) {
        uh[j] = (short)(pw[j] >> 16);
        ul[j] = (short)(pw[j] & 0xffffu);
      }
      st = __builtin_amdgcn_mfma_f32_16x16x32_bf16(uh, xhi[kk], st, 0, 0, 0);
      st = __builtin_amdgcn_mfma_f32_16x16x32_bf16(ul, xhi[kk], st, 0, 0, 0);
      st = __builtin_amdgcn_mfma_f32_16x16x32_bf16(uh, xlo[kk], st, 0, 0, 0);
    }

    // ---- softmax over g (= rows: local 4 + quad shuffles) ----
    float sv0 = st[0] - k2r[0], sv1 = st[1] - k2r[1];
    float sv2 = st[2] - k2r[2], sv3 = st[3] - k2r[3];
    float mx = fmaxf(fmaxf(sv0, sv1), fmaxf(sv2, sv3));
    mx = fmaxf(mx, __shfl_xor(mx, 16));
    mx = fmaxf(mx, __shfl_xor(mx, 32));
    float e0 = __expf(sv0 - mx), e1 = __expf(sv1 - mx);
    float e2 = __expf(sv2 - mx), e3 = __expf(sv3 - mx);
    float sum = e0 + e1 + e2 + e3;
    sum += __shfl_xor(sum, 16);
    sum += __shfl_xor(sum, 32);
    const float inv = 1.f / sum;
    // lane holds attn^T[g=q4*4+r][h=e16]; store as attn[h][g] so the
    // b128 re-read is exactly PV's A-frag (cols 16..31 stay zero).
    at_w[e16 * 40 + q4 * 4 + 0] = f2bf(e0 * inv);
    at_w[e16 * 40 + q4 * 4 + 1] = f2bf(e1 * inv);
    at_w[e16 * 40 + q4 * 4 + 2] = f2bf(e2 * inv);
    at_w[e16 * 40 + q4 * 4 + 3] = f2bf(e3 * inv);

    // ---- PV: out[h][e] = sum_g attn[h][g] * {x,v}[g][e], hi/lo split inputs ----
    const s16x8 af = *(const s16x8*)(at_w + e16 * 40 + q4 * 8);
    f32x4 xm[4], vm[4];
#pragma unroll
    for (int t = 0; t < 4; ++t) { xm[t] = (f32x4)(0.f); vm[t] = (f32x4)(0.f); }
#pragma unroll
    for (int t = 0; t < 4; ++t) {
      s16x8 bxh, bxl, bvh, bvl;
#pragma unroll
      for (int j = 0; j < 8; ++j) {
        const int g = (q4 * 8 + j) & 15;
        const float xv = xb[g * 64 + t * 16 + e16];  // L1/L2 hit
        unsigned short h0 = f2bf(xv);
        bxh[j] = (short)h0;
        bxl[j] = (short)f2bf(xv - bf2f(h0));
        const float vv = vpre[t][j];
        unsigned short h1 = f2bf(vv);
        bvh[j] = (short)h1;
        bvl[j] = (short)f2bf(vv - bf2f(h1));
      }
      xm[t] = __builtin_amdgcn_mfma_f32_16x16x32_bf16(af, bxh, xm[t], 0, 0, 0);
      xm[t] = __builtin_amdgcn_mfma_f32_16x16x32_bf16(af, bxl, xm[t], 0, 0, 0);
      vm[t] = __builtin_amdgcn_mfma_f32_16x16x32_bf16(af, bvh, vm[t], 0, 0, 0);
      vm[t] = __builtin_amdgcn_mfma_f32_16x16x32_bf16(af, bvl, vm[t], 0, 0, 0);
    }

    // ---- store bf16 A rows ----
    unsigned short* ox = Aout + (size_t)b * 1024;
    unsigned short* ov = Aout + (size_t)(B + b) * 1024;
#pragma unroll
    for (int t = 0; t < 4; ++t)
#pragma unroll
      for (int r = 0; r < 4; ++r) {
        const int off = (q4 * 4 + r) * 64 + t * 16 + e16;
        ox[off] = f2bf(xm[t][r]);
        ov[off] = f2bf(vm[t][r]);
      }
  }
}

// ---------------- phase 2: C[M,1024] = A[M,1024] @ Wo^T + bo (bf16 MFMA) ----------------
// m97 structure: 128x128 tile, BK=32, 4 waves 2x2, global_load_lds width 16.
__global__ __launch_bounds__(256) void gemm_bt(
    const unsigned short* __restrict__ A,   // [M][1024] bf16
    const unsigned short* __restrict__ Bw,  // [1024][1024] bf16 (Wo, row = n)
    const float* __restrict__ bias,         // [1024]
    float* __restrict__ C, int M) {
  __shared__ unsigned short As[128 * 32];
  __shared__ unsigned short Bs[128 * 32];

  const int tid = threadIdx.x;
  const int lane = tid & 63;
  const int wave = tid >> 6;
  const int wm = wave >> 1;
  const int wn = wave & 1;
  const int m0 = blockIdx.y * 128;
  const int n0 = blockIdx.x * 128;

  f32x4 acc[4][4];
#pragma unroll
  for (int i = 0; i < 4; ++i)
#pragma unroll
    for (int j = 0; j < 4; ++j) acc[i][j] = (f32x4)(0.f);

  const int row16 = lane & 15;
  const int q8 = (lane >> 4) * 8;

  for (int k0 = 0; k0 < 1024; k0 += 32) {
    __syncthreads();
#pragma unroll
    for (int it = 0; it < 2; ++it) {
      int c = it * 256 + tid;
      int r = c >> 2;
      int ce = (c & 3) * 8;
      const unsigned short* gA = A + (size_t)(m0 + r) * 1024 + k0 + ce;
      const unsigned short* gB = Bw + (size_t)(n0 + r) * 1024 + k0 + ce;
      __builtin_amdgcn_global_load_lds((gvoid_t*)gA, (svoid_t*)(As + c * 8), 16, 0, 0);
      __builtin_amdgcn_global_load_lds((gvoid_t*)gB, (svoid_t*)(Bs + c * 8), 16, 0, 0);
    }
    __syncthreads();

    s16x8 af[4], bfr[4];
#pragma unroll
    for (int i = 0; i < 4; ++i)
      af[i] = *(const s16x8*)(As + (wm * 64 + i * 16 + row16) * 32 + q8);
#pragma unroll
    for (int j = 0; j < 4; ++j)
      bfr[j] = *(const s16x8*)(Bs + (wn * 64 + j * 16 + row16) * 32 + q8);
#pragma unroll
    for (int i = 0; i < 4; ++i)
#pragma unroll
      for (int j = 0; j < 4; ++j)
        acc[i][j] = __builtin_amdgcn_mfma_f32_16x16x32_bf16(af[i], bfr[j], acc[i][j], 0, 0, 0);
  }

  const int col = lane & 15;
  const int qrow = (lane >> 4) * 4;
#pragma unroll
  for (int j = 0; j < 4; ++j) {
    const int n = n0 + wn * 64 + j * 16 + col;
    const float bv = bias[n];
#pragma unroll
    for (int i = 0; i < 4; ++i) {
      const int mbase = m0 + wm * 64 + i * 16 + qrow;
#pragma unroll
      for (int r = 0; r < 4; ++r) {
        C[(size_t)(mbase + r) * 1024 + n] = acc[i][j][r] + bv;
      }
    }
  }
}

extern "C" void kernel_launch(void* const* d_in, const int* in_sizes, int n_in,
                              void* d_out, int out_size, void* d_ws, size_t ws_size,
                              hipStream_t stream) {
  const float* x  = (const float*)d_in[0];
  const float* v  = (const float*)d_in[1];
  const float* Wq = (const float*)d_in[2];
  const float* bq = (const float*)d_in[3];
  const float* Wk = (const float*)d_in[4];
  const float* bk = (const float*)d_in[5];
  const float* Wo = (const float*)d_in[6];
  const float* bo = (const float*)d_in[7];
  float* out = (float*)d_out;

  const int B = in_sizes[0] / 1024;  // 32768
  const int M = 2 * B;               // rows 0..B-1 = x_mixed, B..2B-1 = v_mixed

  unsigned short* Abf  = (unsigned short*)d_ws;                      // M*1024 bf16
  unsigned short* WoBf = (unsigned short*)d_ws + (size_t)M * 1024;   // 1024*1024 bf16

  // Folded-weight scratch lives in the tail of `out`: it is consumed by
  // attn_mfma and only afterwards overwritten by gemm_bt (same stream).
  unsigned short* Phi = (unsigned short*)(out + (size_t)M * 1024 - 16384);
  unsigned short* Plo = Phi + 4096;
  unsigned short* Mhi = Phi + 8192;
  unsigned short* Mlo = Phi + 12288;
  float* cvec = (float*)(Phi + 16384);
  float* kapp = cvec + 64;

  hipLaunchKernelGGL(wo_to_bf16, dim3(4096), dim3(256), 0, stream,
                     Wo, WoBf, 1024 * 1024);
  hipLaunchKernelGGL(prep_attn, dim3(16), dim3(256), 0, stream,
                     Wq, Wk, bq, bk, Phi, Plo, Mhi, Mlo, cvec, kapp);
  hipLaunchKernelGGL(attn_mfma, dim3(2048), dim3(256), 0, stream,
                     x, v, Phi, Plo, Mhi, Mlo, cvec, kapp, Abf, B);
  hipLaunchKernelGGL(gemm_bt, dim3(8, M / 128), dim3(256), 0, stream,
                     Abf, WoBf, bo, out, M);
}